// Round 12
// baseline (2579.330 us; speedup 1.0000x reference)
//
#include <hip/hip_runtime.h>
#include <cfloat>
#include <math.h>

#define NPTS   5000
#define BATCH  2
#define DIM    128
#define NBINS  10
#define BINSZ  500
#define TOPK   5
#define ROTCOLS 100   // rotations stored [128, 100]; we use first NBINS/2 = 5

// ---------------- Kernel A: bin assignment + squared norms (fp64 acc) -----
#define KB_PTS 64
#define KB_STR 129
__global__ void k_bins(const float* __restrict__ pts, const float* __restrict__ rot,
                       int* __restrict__ bin_idx, double* __restrict__ na) {
    __shared__ float P[KB_PTS * KB_STR];
    __shared__ float rotL[DIM * 5];
    int tid = threadIdx.x;
    for (int f = tid; f < DIM * 5; f += 256)
        rotL[f] = rot[(f / 5) * ROTCOLS + (f % 5)];

    int p0  = blockIdx.x * KB_PTS;
    int npb = min(KB_PTS, BATCH * NPTS - p0);

    for (int f = tid; f < npb * DIM; f += 256) {
        int r = f >> 7, d = f & 127;
        P[r * KB_STR + d] = pts[(size_t)(p0 + r) * DIM + d];
    }
    __syncthreads();

    int p = tid >> 2;    // point within block
    int s = tid & 3;     // dim quarter
    double acc[5] = {0., 0., 0., 0., 0.};
    double sq = 0.;
    const float* row = &P[p * KB_STR + s * 32];
    for (int j = 0; j < 32; ++j) {
        double v = (double)row[j];
        sq += v * v;
        int d = s * 32 + j;
#pragma unroll
        for (int h = 0; h < 5; ++h) acc[h] += v * (double)rotL[d * 5 + h];
    }
#pragma unroll
    for (int m = 1; m < 4; m <<= 1) {
#pragma unroll
        for (int h = 0; h < 5; ++h) acc[h] += __shfl_xor(acc[h], m, 4);
        sq += __shfl_xor(sq, m, 4);
    }
    if (s == 0 && p < npb) {
        double best = acc[0]; int bc = 0;
#pragma unroll
        for (int c = 1; c < NBINS; ++c) {
            double v = (c < 5) ? acc[c] : -acc[c - 5];
            if (v > best) { best = v; bc = c; }
        }
        bin_idx[p0 + p] = bc;
        na[p0 + p] = sq;
    }
}

// ---------------- Kernel B: stable counting sort (== stable argsort) ------
__global__ void k_sort(const int* __restrict__ bin_idx, int* __restrict__ order) {
    const int b = blockIdx.x;
    const int t = threadIdx.x;               // 256 threads
    const int NPT = (NPTS + 255) / 256;      // 20
    int start = t * NPT;
    int end   = min(NPTS, start + NPT);

    int cnt[NBINS];
#pragma unroll
    for (int c = 0; c < NBINS; ++c) cnt[c] = 0;
    for (int i = start; i < end; ++i) {
        int c = bin_idx[b * NPTS + i];
#pragma unroll
        for (int k = 0; k < NBINS; ++k) cnt[k] += (c == k);
    }

    __shared__ int hist[NBINS * 256];
#pragma unroll
    for (int c = 0; c < NBINS; ++c) hist[c * 256 + t] = cnt[c];
    __syncthreads();

    int base = t * NBINS;
    int s = 0;
#pragma unroll
    for (int k = 0; k < NBINS; ++k) s += hist[base + k];
    __shared__ int scan[256];
    scan[t] = s;
    __syncthreads();
    for (int off = 1; off < 256; off <<= 1) {
        int v = (t >= off) ? scan[t - off] : 0;
        __syncthreads();
        scan[t] += v;
        __syncthreads();
    }
    int run = scan[t] - s;
#pragma unroll
    for (int k = 0; k < NBINS; ++k) { int h = hist[base + k]; hist[base + k] = run; run += h; }
    __syncthreads();

    int ofs[NBINS];
#pragma unroll
    for (int c = 0; c < NBINS; ++c) ofs[c] = hist[c * 256 + t];
    for (int i = start; i < end; ++i) {
        int c = bin_idx[b * NPTS + i];
        int pos = 0;
#pragma unroll
        for (int k = 0; k < NBINS; ++k) {
            if (c == k) pos = ofs[k];
            ofs[k] += (c == k);
        }
        order[b * NPTS + pos] = i;
    }
}

// -- Kernel C: R10 base + register-prefetch DOUBLE-BUFFERED col tiles ------
// Same decisions/expressions as R10 (absmax 0.0); CTILE 64 -> 2x32 dbuf,
// one barrier per tile, global-load latency hidden under fp64 compute.
#define RT    16
#define NRT   32       // row tiles per chunk
#define CT2   32       // cols per buffer
#define NT2   16       // 500 / 32 (ceil) col tiles
#define RSTRD 130      // rowPd stride in doubles
#define CSTR  132      // colP stride in floats
#define ROWQ  (NPTS/4)

__launch_bounds__(256, 3)
__global__ void k_chunks(const float* __restrict__ pts, const double* __restrict__ na,
                         const int* __restrict__ order, float* __restrict__ out) {
    __shared__ double rowPd[RT * RSTRD];       // 16640 B
    __shared__ float  colP[2][CT2 * CSTR];     // 33792 B
    __shared__ double naC[2][CT2];             // 512 B
    __shared__ double naRs[RT];
    __shared__ int    ordR[RT];                // total ~51.1 KB -> 3 blocks/CU

    int blk   = blockIdx.x;
    int rt    = blk & (NRT - 1);
    int chunk = blk >> 5;          // 0..19
    int b     = chunk / NBINS;
    int c     = chunk % NBINS;
    int tid   = threadIdx.x;
    int row0  = rt * RT;
    int rowCount = min(RT, BINSZ - row0);   // 16, last rowtile: 4

    const int*   ordBase = order + b * NPTS + c * BINSZ;
    const float* ptsB    = pts + (size_t)b * NPTS * DIM;

    // stage rows as fp64 (cvt once)
    for (int f = tid; f < rowCount * (DIM / 4); f += 256) {
        int r = f >> 5;
        int q = f & 31;
        int g = ordBase[row0 + r];
        float4 v = *(const float4*)(ptsB + (size_t)g * DIM + q * 4);
        double2 d01; d01.x = (double)v.x; d01.y = (double)v.y;
        double2 d23; d23.x = (double)v.z; d23.y = (double)v.w;
        *(double2*)(&rowPd[r * RSTRD + q * 4 + 0]) = d01;
        *(double2*)(&rowPd[r * RSTRD + q * 4 + 2]) = d23;
    }
    if (tid < rowCount) {
        int g = ordBase[row0 + tid];
        ordR[tid] = g;
        naRs[tid] = na[b * NPTS + g];
    }

    // stage col tile 0 into buffer 0 (each thread: one 64B chunk of one col)
    {
        int j  = tid >> 3;          // col 0..31
        int qq = (tid & 7) * 4;     // float4 index 0,4,..,28
        int g = ordBase[j];
        const float4* s4 = (const float4*)(ptsB + (size_t)g * DIM);
        float4 v0 = s4[qq], v1 = s4[qq + 1], v2 = s4[qq + 2], v3 = s4[qq + 3];
        float4* d4 = (float4*)(&colP[0][j * CSTR + qq * 4]);
        d4[0] = v0; d4[1] = v1; d4[2] = v2; d4[3] = v3;
        if (tid < CT2) naC[0][tid] = na[b * NPTS + ordBase[tid]];
    }
    __syncthreads();

    int rg = tid >> 5;   // 0..7 : rows rg, rg+8
    int cg = tid & 31;   // 0..31: col cg within tile

    double naRr0 = (rg     < rowCount) ? naRs[rg]     : 0.;
    double naRr1 = (rg + 8 < rowCount) ? naRs[rg + 8] : 0.;

    double tv[2][TOPK];
    int    tl[2][TOPK];
#pragma unroll
    for (int ii = 0; ii < 2; ++ii)
#pragma unroll
        for (int k = 0; k < TOPK; ++k) { tv[ii][k] = DBL_MAX; tl[ii][k] = 0x7fffffff; }

    const int totalZ = rowCount * ROWQ;
    const int pj  = tid >> 3;
    const int pq  = (tid & 7) * 4;

    for (int t = 0; t < NT2; ++t) {
        int cur = t & 1, nxt = cur ^ 1;
        int col0 = t * CT2;
        int colCount = min(CT2, BINSZ - col0);   // 32, last tile: 20

        // issue next tile's global loads into registers (latency hides below)
        float4 p0, p1, p2, p3;
        bool doPre = false, doNa = false;
        double nna = 0.;
        if (t < NT2 - 1) {
            int ncol0 = col0 + CT2;
            int ncc = min(CT2, BINSZ - ncol0);
            if (pj < ncc) {
                int g = ordBase[ncol0 + pj];
                const float4* s4 = (const float4*)(ptsB + (size_t)g * DIM);
                p0 = s4[pq]; p1 = s4[pq + 1]; p2 = s4[pq + 2]; p3 = s4[pq + 3];
                doPre = true;
            }
            if (tid < ncc) { nna = na[b * NPTS + ordBase[ncol0 + tid]]; doNa = true; }
        }

        // zero-fill slice t (drains during compute; final barrier orders it)
        {
            float4 z = make_float4(0.f, 0.f, 0.f, 0.f);
            int z0 = (t * totalZ) / NT2, z1 = ((t + 1) * totalZ) / NT2;
            for (int f = z0 + tid; f < z1; f += 256) {
                int r = f / ROWQ;
                int q = f - r * ROWQ;
                float* outRow = out + ((size_t)b * NPTS + ordR[r]) * NPTS;
                *(float4*)(outRow + 4 * q) = z;
            }
        }

        // fp64 gram: rows {rg, rg+8} x col cg (expressions verbatim R10)
        double acc0 = 0., acc1 = 0.;
        for (int q = 0; q < DIM / 4; ++q) {
            double2 a0lo = *(const double2*)(&rowPd[rg * RSTRD + q * 4 + 0]);
            double2 a0hi = *(const double2*)(&rowPd[rg * RSTRD + q * 4 + 2]);
            double2 a1lo = *(const double2*)(&rowPd[(rg + 8) * RSTRD + q * 4 + 0]);
            double2 a1hi = *(const double2*)(&rowPd[(rg + 8) * RSTRD + q * 4 + 2]);
            float4 bv = *(const float4*)(&colP[cur][cg * CSTR + q * 4]);
            double b0 = (double)bv.x, b1 = (double)bv.y,
                   b2 = (double)bv.z, b3 = (double)bv.w;
            acc0 += a0lo.x * b0 + a0lo.y * b1 + a0hi.x * b2 + a0hi.y * b3;
            acc1 += a1lo.x * b0 + a1lo.y * b1 + a1hi.x * b2 + a1hi.y * b3;
        }

        // running bottom-5 (per-thread cols cg, cg+32, ... increasing w/ t)
        if (cg < colCount) {
            int    cl = col0 + cg;
            double nc = naC[cur][cg];
            double cv0 = fmax(naRr0 + nc - 2. * acc0, 1e-6);
            double cv1 = fmax(naRr1 + nc - 2. * acc1, 1e-6);
            int cl0 = cl, cl1 = cl;
#pragma unroll
            for (int k = 0; k < TOPK; ++k) {   // strict <: equal keeps earlier idx
                bool lt0 = (cv0 < tv[0][k]);
                double ov0 = tv[0][k]; int ol0 = tl[0][k];
                if (lt0) { tv[0][k] = cv0; tl[0][k] = cl0; cv0 = ov0; cl0 = ol0; }
                bool lt1 = (cv1 < tv[1][k]);
                double ov1 = tv[1][k]; int ol1 = tl[1][k];
                if (lt1) { tv[1][k] = cv1; tl[1][k] = cl1; cv1 = ov1; cl1 = ol1; }
            }
        }

        // commit prefetched tile into the alternate buffer, then one barrier
        if (doPre) {
            float4* d4 = (float4*)(&colP[nxt][pj * CSTR + pq * 4]);
            d4[0] = p0; d4[1] = p1; d4[2] = p2; d4[3] = p3;
        }
        if (doNa) naC[nxt][tid] = nna;
        __syncthreads();
    }

    // merge across the 32 column-threads of each row (butterfly, width 32)
#pragma unroll
    for (int m = 1; m < 32; m <<= 1) {
#pragma unroll
        for (int ii = 0; ii < 2; ++ii) {
            double rv[TOPK]; int rl[TOPK];
#pragma unroll
            for (int k = 0; k < TOPK; ++k) {
                rv[k] = __shfl_xor(tv[ii][k], m, 32);
                rl[k] = __shfl_xor(tl[ii][k], m, 32);
            }
#pragma unroll
            for (int k = 0; k < TOPK; ++k) {
                double cv = rv[k]; int cl = rl[k];
#pragma unroll
                for (int s = 0; s < TOPK; ++s) {   // (key asc, idx asc) total order
                    bool better = (cv < tv[ii][s]) || (cv == tv[ii][s] && cl < tl[ii][s]);
                    double ov = tv[ii][s]; int ol = tl[ii][s];
                    if (better) { tv[ii][s] = cv; tl[ii][s] = cl; cv = ov; cl = ol; }
                }
            }
        }
    }

    // scatter: lane cg==0 of each row-group writes 2 rows x 5 values
    // (zero-fill fully drained by the loop's final __syncthreads)
    if (cg == 0) {
#pragma unroll
        for (int ii = 0; ii < 2; ++ii) {
            int r = rg + 8 * ii;
            if (r < rowCount) {
                int src = ordR[r];
                float* outRow = out + ((size_t)b * NPTS + src) * NPTS;
#pragma unroll
                for (int k = 0; k < TOPK; ++k) {
                    double dist = sqrt(tv[ii][k]);     // tv already clamped
                    double dm   = exp(-0.1 * dist);
                    int dst = ordBase[tl[ii][k]];      // bin-local -> global
                    outRow[dst] = (float)dm;
                }
            }
        }
    }
}

// ---------------- launch ----------------
extern "C" void kernel_launch(void* const* d_in, const int* in_sizes, int n_in,
                              void* d_out, int out_size, void* d_ws, size_t ws_size,
                              hipStream_t stream) {
    const float* pts = (const float*)d_in[0];   // [2,5000,128]
    const float* rot = (const float*)d_in[1];   // [128,100]
    float* out = (float*)d_out;                 // [2,5000,5000]

    double* na      = (double*)d_ws;                                    // 80000 B
    int*    bin_idx = (int*)((char*)d_ws + 80000);                      // 40000 B
    int*    order   = (int*)((char*)d_ws + 120000);                     // 40000 B

    k_bins<<<(BATCH * NPTS + KB_PTS - 1) / KB_PTS, 256, 0, stream>>>(pts, rot, bin_idx, na);
    k_sort<<<BATCH, 256, 0, stream>>>(bin_idx, order);
    k_chunks<<<BATCH * NBINS * NRT, 256, 0, stream>>>(pts, na, order, out);
}

// Round 13
// 295.941 us; speedup vs baseline: 8.7157x; 8.7157x over previous
//
#include <hip/hip_runtime.h>
#include <cfloat>
#include <math.h>

#define NPTS   5000
#define BATCH  2
#define DIM    128
#define NBINS  10
#define BINSZ  500
#define TOPK   5
#define ROTCOLS 100   // rotations stored [128, 100]; we use first NBINS/2 = 5

// ---------------- Kernel A: bin assignment + squared norms (fp64 acc) -----
#define KB_PTS 64
#define KB_STR 129
__global__ void k_bins(const float* __restrict__ pts, const float* __restrict__ rot,
                       int* __restrict__ bin_idx, double* __restrict__ na) {
    __shared__ float P[KB_PTS * KB_STR];
    __shared__ float rotL[DIM * 5];
    int tid = threadIdx.x;
    for (int f = tid; f < DIM * 5; f += 256)
        rotL[f] = rot[(f / 5) * ROTCOLS + (f % 5)];

    int p0  = blockIdx.x * KB_PTS;
    int npb = min(KB_PTS, BATCH * NPTS - p0);

    for (int f = tid; f < npb * DIM; f += 256) {
        int r = f >> 7, d = f & 127;
        P[r * KB_STR + d] = pts[(size_t)(p0 + r) * DIM + d];
    }
    __syncthreads();

    int p = tid >> 2;    // point within block
    int s = tid & 3;     // dim quarter
    double acc[5] = {0., 0., 0., 0., 0.};
    double sq = 0.;
    const float* row = &P[p * KB_STR + s * 32];
    for (int j = 0; j < 32; ++j) {
        double v = (double)row[j];
        sq += v * v;
        int d = s * 32 + j;
#pragma unroll
        for (int h = 0; h < 5; ++h) acc[h] += v * (double)rotL[d * 5 + h];
    }
#pragma unroll
    for (int m = 1; m < 4; m <<= 1) {
#pragma unroll
        for (int h = 0; h < 5; ++h) acc[h] += __shfl_xor(acc[h], m, 4);
        sq += __shfl_xor(sq, m, 4);
    }
    if (s == 0 && p < npb) {
        double best = acc[0]; int bc = 0;
#pragma unroll
        for (int c = 1; c < NBINS; ++c) {
            double v = (c < 5) ? acc[c] : -acc[c - 5];
            if (v > best) { best = v; bc = c; }
        }
        bin_idx[p0 + p] = bc;
        na[p0 + p] = sq;
    }
}

// ---------------- Kernel B: stable counting sort (== stable argsort) ------
__global__ void k_sort(const int* __restrict__ bin_idx, int* __restrict__ order) {
    const int b = blockIdx.x;
    const int t = threadIdx.x;               // 256 threads
    const int NPT = (NPTS + 255) / 256;      // 20
    int start = t * NPT;
    int end   = min(NPTS, start + NPT);

    int cnt[NBINS];
#pragma unroll
    for (int c = 0; c < NBINS; ++c) cnt[c] = 0;
    for (int i = start; i < end; ++i) {
        int c = bin_idx[b * NPTS + i];
#pragma unroll
        for (int k = 0; k < NBINS; ++k) cnt[k] += (c == k);
    }

    __shared__ int hist[NBINS * 256];
#pragma unroll
    for (int c = 0; c < NBINS; ++c) hist[c * 256 + t] = cnt[c];
    __syncthreads();

    int base = t * NBINS;
    int s = 0;
#pragma unroll
    for (int k = 0; k < NBINS; ++k) s += hist[base + k];
    __shared__ int scan[256];
    scan[t] = s;
    __syncthreads();
    for (int off = 1; off < 256; off <<= 1) {
        int v = (t >= off) ? scan[t - off] : 0;
        __syncthreads();
        scan[t] += v;
        __syncthreads();
    }
    int run = scan[t] - s;
#pragma unroll
    for (int k = 0; k < NBINS; ++k) { int h = hist[base + k]; hist[base + k] = run; run += h; }
    __syncthreads();

    int ofs[NBINS];
#pragma unroll
    for (int c = 0; c < NBINS; ++c) ofs[c] = hist[c * 256 + t];
    for (int i = start; i < end; ++i) {
        int c = bin_idx[b * NPTS + i];
        int pos = 0;
#pragma unroll
        for (int k = 0; k < NBINS; ++k) {
            if (c == k) pos = ofs[k];
            ofs[k] += (c == k);
        }
        order[b * NPTS + pos] = i;
    }
}

// -- Kernel C: fp64 gram (rowP staged as fp64) + top-5 + zero-fill/scatter --
// Verified optimum (R10): 124us, absmax 0.0. Pipelining variants (register
// prefetch, 8-wide candidate state, one-barrier restructure) all regressed
// 1.6-20x via GB-scale unattributed private-memory traffic — do not revisit
// without disasm evidence.
#define RT    16
#define NRT   32
#define CTILE 64
#define RSTRD 130      // rowPd stride in doubles (1040 B rows, 16B-aligned)
#define CSTR  132      // colP stride in floats
#define NCT   8
#define ROWQ  (NPTS/4)

__launch_bounds__(256, 3)
__global__ void k_chunks(const float* __restrict__ pts, const double* __restrict__ na,
                         const int* __restrict__ order, float* __restrict__ out) {
    __shared__ double rowPd[RT * RSTRD];    // 16640 B
    __shared__ float  colP[CTILE * CSTR];   // 33792 B
    __shared__ double naC[CTILE];
    __shared__ double naRs[RT];
    __shared__ int    ordR[RT];             // ~51.1 KB -> 3 blocks/CU

    int blk   = blockIdx.x;
    int rt    = blk & (NRT - 1);
    int chunk = blk >> 5;          // 0..19
    int b     = chunk / NBINS;
    int c     = chunk % NBINS;
    int tid   = threadIdx.x;
    int row0  = rt * RT;
    int rowCount = min(RT, BINSZ - row0);   // 16, except last tile: 4

    const int*   ordBase = order + b * NPTS + c * BINSZ;
    const float* ptsB    = pts + (size_t)b * NPTS * DIM;

    // stage row points as doubles (gathered via order; cvt once per element)
    for (int f = tid; f < rowCount * (DIM / 4); f += 256) {
        int r = f >> 5;
        int q = f & 31;
        int g = ordBase[row0 + r];
        float4 v = *(const float4*)(ptsB + (size_t)g * DIM + q * 4);
        double2 d01; d01.x = (double)v.x; d01.y = (double)v.y;
        double2 d23; d23.x = (double)v.z; d23.y = (double)v.w;
        *(double2*)(&rowPd[r * RSTRD + q * 4 + 0]) = d01;
        *(double2*)(&rowPd[r * RSTRD + q * 4 + 2]) = d23;
    }
    if (tid < rowCount) {
        int g = ordBase[row0 + tid];
        ordR[tid] = g;
        naRs[tid] = na[b * NPTS + g];
    }
    __syncthreads();

    int rg = tid >> 5;   // 0..7 : rows rg, rg+8
    int cg = tid & 31;   // 0..31: cols cg, cg+32

    double naRr0 = (rg     < rowCount) ? naRs[rg]     : 0.;
    double naRr1 = (rg + 8 < rowCount) ? naRs[rg + 8] : 0.;

    // selection key: clamped squared distance (smaller = better); bottom-5,
    // strict < with in-order arrival == (key asc, idx asc), matches ref.
    double tv[2][TOPK];
    int    tl[2][TOPK];
#pragma unroll
    for (int ii = 0; ii < 2; ++ii)
#pragma unroll
        for (int k = 0; k < TOPK; ++k) { tv[ii][k] = DBL_MAX; tl[ii][k] = 0x7fffffff; }

    const int totalZ = rowCount * ROWQ;

    for (int ct = 0; ct < NCT; ++ct) {
        int col0 = ct * CTILE;
        int colCount = min(CTILE, BINSZ - col0);
        __syncthreads();   // prev tile's readers done before restage
        for (int f = tid; f < colCount * (DIM / 4); f += 256) {
            int j = f >> 5;
            int q = f & 31;
            int g = ordBase[col0 + j];
            float4 v = *(const float4*)(ptsB + (size_t)g * DIM + q * 4);
            *(float4*)(&colP[j * CSTR + q * 4]) = v;
        }
        if (tid < colCount) {
            int g = ordBase[col0 + tid];
            naC[tid] = na[b * NPTS + g];
        }
        __syncthreads();

        // zero-fill slice ct: stores drain during this tile's gram compute
        {
            float4 z = make_float4(0.f, 0.f, 0.f, 0.f);
            int z0 = (ct * totalZ) / NCT, z1 = ((ct + 1) * totalZ) / NCT;
            for (int f = z0 + tid; f < z1; f += 256) {
                int r = f / ROWQ;
                int q = f - r * ROWQ;
                float* outRow = out + ((size_t)b * NPTS + ordR[r]) * NPTS;
                *(float4*)(outRow + 4 * q) = z;
            }
        }

        double acc00 = 0., acc01 = 0., acc10 = 0., acc11 = 0.;

        for (int q = 0; q < DIM / 4; ++q) {
            double2 a0lo = *(const double2*)(&rowPd[rg * RSTRD + q * 4 + 0]);
            double2 a0hi = *(const double2*)(&rowPd[rg * RSTRD + q * 4 + 2]);
            double2 a1lo = *(const double2*)(&rowPd[(rg + 8) * RSTRD + q * 4 + 0]);
            double2 a1hi = *(const double2*)(&rowPd[(rg + 8) * RSTRD + q * 4 + 2]);
            float4 b0 = *(const float4*)(&colP[cg * CSTR + q * 4]);
            float4 b1 = *(const float4*)(&colP[(cg + 32) * CSTR + q * 4]);
            double b00 = (double)b0.x, b01 = (double)b0.y,
                   b02 = (double)b0.z, b03 = (double)b0.w;
            double b10 = (double)b1.x, b11 = (double)b1.y,
                   b12 = (double)b1.z, b13 = (double)b1.w;
            acc00 += a0lo.x * b00 + a0lo.y * b01 + a0hi.x * b02 + a0hi.y * b03;
            acc01 += a0lo.x * b10 + a0lo.y * b11 + a0hi.x * b12 + a0hi.y * b13;
            acc10 += a1lo.x * b00 + a1lo.y * b01 + a1hi.x * b02 + a1hi.y * b03;
            acc11 += a1lo.x * b10 + a1lo.y * b11 + a1hi.x * b12 + a1hi.y * b13;
        }

        // running bottom-5 (per thread, candidates arrive in increasing idx:
        // cols cg then cg+32, tiles increasing)
#pragma unroll
        for (int jj = 0; jj < 2; ++jj) {
            int j = cg + 32 * jj;
            if (j < colCount) {
                int    cl = col0 + j;
                double nc = naC[j];
                double a0 = (jj == 0) ? acc00 : acc01;
                double a1 = (jj == 0) ? acc10 : acc11;
                double cv0 = fmax(naRr0 + nc - 2. * a0, 1e-6);
                double cv1 = fmax(naRr1 + nc - 2. * a1, 1e-6);
                int cl0 = cl, cl1 = cl;
#pragma unroll
                for (int k = 0; k < TOPK; ++k) {   // strict <: equal keeps earlier idx
                    bool lt0 = (cv0 < tv[0][k]);
                    double ov0 = tv[0][k]; int ol0 = tl[0][k];
                    if (lt0) { tv[0][k] = cv0; tl[0][k] = cl0; cv0 = ov0; cl0 = ol0; }
                    bool lt1 = (cv1 < tv[1][k]);
                    double ov1 = tv[1][k]; int ol1 = tl[1][k];
                    if (lt1) { tv[1][k] = cv1; tl[1][k] = cl1; cv1 = ov1; cl1 = ol1; }
                }
            }
        }
    }

    // merge across the 32 column-threads of each row (butterfly, width 32)
#pragma unroll
    for (int m = 1; m < 32; m <<= 1) {
#pragma unroll
        for (int ii = 0; ii < 2; ++ii) {
            double rv[TOPK]; int rl[TOPK];
#pragma unroll
            for (int k = 0; k < TOPK; ++k) {
                rv[k] = __shfl_xor(tv[ii][k], m, 32);
                rl[k] = __shfl_xor(tl[ii][k], m, 32);
            }
#pragma unroll
            for (int k = 0; k < TOPK; ++k) {
                double cv = rv[k]; int cl = rl[k];
#pragma unroll
                for (int s = 0; s < TOPK; ++s) {   // (key asc, idx asc) total order
                    bool better = (cv < tv[ii][s]) || (cv == tv[ii][s] && cl < tl[ii][s]);
                    double ov = tv[ii][s]; int ol = tl[ii][s];
                    if (better) { tv[ii][s] = cv; tl[ii][s] = cl; cv = ov; cl = ol; }
                }
            }
        }
    }

    __syncthreads();   // drain last zero slice before value scatter

    // scatter: lane cg==0 of each row-group writes 2 rows x 5 values
    if (cg == 0) {
#pragma unroll
        for (int ii = 0; ii < 2; ++ii) {
            int r = rg + 8 * ii;
            if (r < rowCount) {
                int src = ordR[r];
                float* outRow = out + ((size_t)b * NPTS + src) * NPTS;
#pragma unroll
                for (int k = 0; k < TOPK; ++k) {
                    double dist = sqrt(tv[ii][k]);     // tv already clamped
                    double dm   = exp(-0.1 * dist);
                    int dst = ordBase[tl[ii][k]];      // chunk-local -> global
                    outRow[dst] = (float)dm;
                }
            }
        }
    }
}

// ---------------- launch ----------------
extern "C" void kernel_launch(void* const* d_in, const int* in_sizes, int n_in,
                              void* d_out, int out_size, void* d_ws, size_t ws_size,
                              hipStream_t stream) {
    const float* pts = (const float*)d_in[0];   // [2,5000,128]
    const float* rot = (const float*)d_in[1];   // [128,100]
    float* out = (float*)d_out;                 // [2,5000,5000]

    double* na      = (double*)d_ws;                                    // 80000 B
    int*    bin_idx = (int*)((char*)d_ws + 80000);                      // 40000 B
    int*    order   = (int*)((char*)d_ws + 120000);                     // 40000 B

    k_bins<<<(BATCH * NPTS + KB_PTS - 1) / KB_PTS, 256, 0, stream>>>(pts, rot, bin_idx, na);
    k_sort<<<BATCH, 256, 0, stream>>>(bin_idx, order);
    k_chunks<<<BATCH * NBINS * NRT, 256, 0, stream>>>(pts, na, order, out);
}